// Round 3
// baseline (2857.403 us; speedup 1.0000x reference)
//
#include <hip/hip_runtime.h>

typedef unsigned short u16;
typedef unsigned int u32;
typedef __bf16 bf16x8 __attribute__((ext_vector_type(8)));
typedef float f32x4 __attribute__((ext_vector_type(4)));
typedef u16 u16x4 __attribute__((ext_vector_type(4)));

#define S_LEN 2048
#define NH 16
#define DH 64
#define DM 1024

#define GLDS(gp, lp) __builtin_amdgcn_global_load_lds( \
    (const __attribute__((address_space(1))) void*)(gp), \
    (__attribute__((address_space(3))) void*)(lp), 16, 0, 0)

__device__ __forceinline__ u16 f2bf(float f) {
  unsigned u = __float_as_uint(f);
  u += 0x7FFFu + ((u >> 16) & 1u);
  return (u16)(u >> 16);
}
__device__ __forceinline__ float bf2f(u16 h) {
  return __uint_as_float(((unsigned)h) << 16);
}

// ---------------- convert f32 -> bf16 ----------------
__global__ __launch_bounds__(256) void conv_kernel(const float* __restrict__ in,
                                                   u16* __restrict__ out, int n) {
  int i = (blockIdx.x * 256 + threadIdx.x) * 4;
  if (i >= n) return;
  float4 v = *(const float4*)(in + i);
  u16x4 o;
  o.x = f2bf(v.x); o.y = f2bf(v.y); o.z = f2bf(v.z); o.w = f2bf(v.w);
  *(u16x4*)(out + i) = o;
}

// ---------------- bf16 GEMM: C[M][N] = A[M][K] * B[N][K]^T ----------------
// 128x128 tile, BK=32, 4 waves, global_load_lds width-16 staging (m97 pattern).
template <int OUTF32>
__global__ __launch_bounds__(256) void gemm_bt(const u16* __restrict__ A,
                                               const u16* __restrict__ B,
                                               void* __restrict__ C,
                                               int N, int K) {
  __shared__ __align__(16) u16 smem[8192];
  u16* abuf = smem;
  u16* bbuf = smem + 4096;
  int tid = threadIdx.x;
  int w = tid >> 6, l = tid & 63, lg = l >> 4, lr = l & 15;
  int m0 = blockIdx.y * 128, n0 = blockIdx.x * 128;
  int wm = (w >> 1) * 64, wn = (w & 1) * 64;
  int NK = K >> 5;

  int srow[2], scol[2];
#pragma unroll
  for (int i = 0; i < 2; ++i) {
    srow[i] = (i * 4 + w) * 16 + (l >> 2);
    scol[i] = (l & 3) * 8;
  }

  f32x4 zero4 = {0.f, 0.f, 0.f, 0.f};
  f32x4 acc[4][4];
#pragma unroll
  for (int mt = 0; mt < 4; ++mt)
#pragma unroll
    for (int nt = 0; nt < 4; ++nt) acc[mt][nt] = zero4;

  for (int kt = 0; kt < NK; ++kt) {
    __syncthreads();  // previous iter's readers done
#pragma unroll
    for (int i = 0; i < 2; ++i) {
      GLDS(A + (size_t)(m0 + srow[i]) * K + kt * 32 + scol[i], abuf + (i * 4 + w) * 512);
      GLDS(B + (size_t)(n0 + srow[i]) * K + kt * 32 + scol[i], bbuf + (i * 4 + w) * 512);
    }
    __syncthreads();  // staged tile visible (vmcnt drained by sync)

    bf16x8 af[4], bfr[4];
#pragma unroll
    for (int mt = 0; mt < 4; ++mt)
      af[mt] = *(const bf16x8*)(abuf + (wm + mt * 16 + lr) * 32 + lg * 8);
#pragma unroll
    for (int nt = 0; nt < 4; ++nt)
      bfr[nt] = *(const bf16x8*)(bbuf + (wn + nt * 16 + lr) * 32 + lg * 8);
    __builtin_amdgcn_s_setprio(1);
#pragma unroll
    for (int mt = 0; mt < 4; ++mt)
#pragma unroll
      for (int nt = 0; nt < 4; ++nt)
        acc[mt][nt] = __builtin_amdgcn_mfma_f32_16x16x32_bf16(af[mt], bfr[nt], acc[mt][nt], 0, 0, 0);
    __builtin_amdgcn_s_setprio(0);
  }

#pragma unroll
  for (int mt = 0; mt < 4; ++mt)
#pragma unroll
    for (int nt = 0; nt < 4; ++nt)
#pragma unroll
      for (int r = 0; r < 4; ++r) {
        int row = m0 + wm + mt * 16 + lg * 4 + r;
        int col = n0 + wn + nt * 16 + lr;
        float v = acc[mt][nt][r];
        if (OUTF32) ((float*)C)[(size_t)row * N + col] = v;
        else        ((u16*)C)[(size_t)row * N + col] = f2bf(v);
      }
}

// ---------------- RoPE + head-major layout + V transpose ----------------
// Q is pre-scaled by 1/sqrt(dh) = 0.125 here.
__global__ __launch_bounds__(256) void rope_kernel(const u16* __restrict__ qkv,
                                                   const float* __restrict__ pi_gate_logit,
                                                   u16* __restrict__ qrot,
                                                   u16* __restrict__ krot,
                                                   u16* __restrict__ vt) {
  int st = blockIdx.x;   // s tile (0..31)
  int bh = blockIdx.y;   // b*16+h
  int h = bh & 15;
  int t = threadIdx.x;
  int sl = t >> 2;       // 0..63
  int pb = t & 3;
  int d0 = pb * 16;
  int s = st * 64 + sl;
  int b = bh >> 4;
  size_t rowg = (size_t)(b * S_LEN + s) * (3 * DM) + h * DH + d0;

  float pg = 1.0f / (1.0f + __expf(-pi_gate_logit[h]));
  float spos = (float)s;
  float cs[8], sn[8];
#pragma unroll
  for (int j = 0; j < 8; ++j) {
    float p = (float)(pb * 8 + j);
    float fr = exp2f((1.0f - p * 0.03125f) * 1.6514961294723187f);  // pi^(1-p/32)
    float th = (spos * fr) * pg;
    float rev = th * 0.15915494309189535f;
    rev = rev - floorf(rev);
    cs[j] = __builtin_amdgcn_cosf(rev);
    sn[j] = __builtin_amdgcn_sinf(rev);
  }

#pragma unroll
  for (int which = 0; which < 2; ++which) {
    const u16* src = qkv + rowg + (size_t)which * DM;
    float sc = which ? 1.0f : 0.125f;
    u16 in[16], ou[16];
    *(bf16x8*)(in)     = *(const bf16x8*)(src);
    *(bf16x8*)(in + 8) = *(const bf16x8*)(src + 8);
#pragma unroll
    for (int j = 0; j < 8; ++j) {
      float t1 = bf2f(in[2 * j]), t2 = bf2f(in[2 * j + 1]);
      ou[2 * j]     = f2bf((t1 * cs[j] - t2 * sn[j]) * sc);
      ou[2 * j + 1] = f2bf((t1 * sn[j] + t2 * cs[j]) * sc);
    }
    u16* dst = (which ? krot : qrot) + ((size_t)bh * S_LEN + s) * DH + d0;
    *(bf16x8*)(dst)     = *(bf16x8*)(ou);
    *(bf16x8*)(dst + 8) = *(bf16x8*)(ou + 8);
  }

  {
    const u16* src = qkv + rowg + 2 * DM;
    u16 in[16];
    *(bf16x8*)(in)     = *(const bf16x8*)(src);
    *(bf16x8*)(in + 8) = *(const bf16x8*)(src + 8);
#pragma unroll
    for (int e = 0; e < 16; ++e)
      vt[((size_t)bh * DH + d0 + e) * S_LEN + st * 64 + sl] = in[e];
  }
}

// ---------------- flash attention (causal + linear decay bias) ----------------
// Barrier-free: K/V fragments loaded directly from global (L1/L2-resident,
// 4 waves per block share tiles). Swapped QK^T for in-lane softmax.
// Heavy-first grid: qt = 31 - blockIdx.y.
__global__ __launch_bounds__(256) void attn_kernel(const u16* __restrict__ qrot,
                                                   const u16* __restrict__ krot,
                                                   const u16* __restrict__ vt,
                                                   const float* __restrict__ log_xi,
                                                   const float* __restrict__ e_gate_logit,
                                                   u16* __restrict__ attnout) {
  int bh = blockIdx.x;
  int qt = 31 - blockIdx.y;
  int b = bh >> 4, h = bh & 15;
  int tid = threadIdx.x, w = tid >> 6, l = tid & 63, lg = l >> 4, lr = l & 15;
  int q0 = qt * 64;
  int il = w * 16 + lr;  // this lane's q-row, local to the 64-row tile

  float eg = 1.0f / (1.0f + __expf(-e_gate_logit[h]));
  float cdec = eg * __expf(-log_xi[h]);  // e_g / xi

  __shared__ __align__(16) unsigned char smem[8192];
  unsigned char* pbuf = smem + (w << 11);  // 2KB per wave, private

  const size_t bhS = (size_t)bh * S_LEN;
  const u16* kb0 = krot + bhS * DH;
  const u16* vb0 = vt + (size_t)bh * DH * S_LEN;

  bf16x8 qf[2];
  {
    const u16* qp = qrot + (bhS + q0 + il) * DH + lg * 8;
    qf[0] = *(const bf16x8*)(qp);
    qf[1] = *(const bf16x8*)(qp + 32);
  }

  // column bias: (kv_local)*cdec for this lane's 16 score slots
  float cbv[16];
#pragma unroll
  for (int nt = 0; nt < 4; ++nt)
#pragma unroll
    for (int r = 0; r < 4; ++r)
      cbv[nt * 4 + r] = (float)(nt * 16 + lg * 4 + r) * cdec;

  f32x4 zero4 = {0.f, 0.f, 0.f, 0.f};
  f32x4 oacc[4];
#pragma unroll
  for (int nt = 0; nt < 4; ++nt) oacc[nt] = zero4;
  float mrun = -1e30f, lrun = 0.f;
  float tb = 0.f;  // t*64*cdec

  for (int t = 0; t <= qt; ++t, tb += 64.f * cdec) {
    bool diag = (t == qt);
    const u16* kb = kb0 + (size_t)t * 64 * DH;
    const u16* vb = vb0 + t * 64;

    // ---- QK^T (swapped): sacc[nt] = S^T[kv=nt*16+lg*4+r][q=lr] ----
    f32x4 sacc[4];
#pragma unroll
    for (int nt = 0; nt < 4; ++nt) sacc[nt] = zero4;
    int ntmax = diag ? (w + 1) : 4;   // wave-uniform; nt>w fully masked on diagonal
    for (int nt = 0; nt < ntmax; ++nt) {
      bf16x8 kfa = *(const bf16x8*)(kb + (nt * 16 + lr) * DH + lg * 8);
      bf16x8 kfb = *(const bf16x8*)(kb + (nt * 16 + lr) * DH + 32 + lg * 8);
      __builtin_amdgcn_s_setprio(1);
      sacc[nt] = __builtin_amdgcn_mfma_f32_16x16x32_bf16(kfa, qf[0], sacc[nt], 0, 0, 0);
      sacc[nt] = __builtin_amdgcn_mfma_f32_16x16x32_bf16(kfb, qf[1], sacc[nt], 0, 0, 0);
      __builtin_amdgcn_s_setprio(0);
    }

    // ---- V fragments (issue early; latency hides under softmax VALU) ----
    int kkmax = (diag && w < 2) ? 1 : 2;  // kv>=32 fully masked for waves 0,1 on diagonal
    bf16x8 vf[4][2];
#pragma unroll
    for (int nt = 0; nt < 4; ++nt)
      for (int kk = 0; kk < kkmax; ++kk)
        vf[nt][kk] = *(const bf16x8*)(vb + (size_t)(nt * 16 + lr) * S_LEN + kk * 32 + lg * 8);

    // ---- scores + bias + (diagonal) causal mask ----
    float pv[16];
#pragma unroll
    for (int nt = 0; nt < 4; ++nt)
#pragma unroll
      for (int r = 0; r < 4; ++r) {
        int i16 = nt * 4 + r;
        float v = sacc[nt][r] + (tb + cbv[i16]);
        if (diag) {
          int jl = nt * 16 + lg * 4 + r;
          v = (jl <= il) ? v : -1e30f;
        }
        pv[i16] = v;
      }

    // ---- row max: in-lane tree + 2 shuffles ----
    float m1 = pv[0];
#pragma unroll
    for (int i = 1; i < 16; ++i) m1 = fmaxf(m1, pv[i]);
    m1 = fmaxf(m1, __shfl_xor(m1, 16));
    m1 = fmaxf(m1, __shfl_xor(m1, 32));

    // ---- defer-max rescale (THR=8) ----
    if (__ballot(m1 > mrun + 8.f)) {
      float mnew = fmaxf(mrun, m1);
      float fac = __expf(mrun - mnew);
      mrun = mnew;
      lrun *= fac;
      int fi = __float_as_int(fac);
      float facr[4];
#pragma unroll
      for (int r = 0; r < 4; ++r)
        facr[r] = __int_as_float(__builtin_amdgcn_ds_bpermute((4 * lg + r) << 2, fi));
#pragma unroll
      for (int nt = 0; nt < 4; ++nt)
#pragma unroll
        for (int r = 0; r < 4; ++r) oacc[nt][r] *= facr[r];
    }

    // ---- exp + row sum ----
    float p[16];
    float rsum = 0.f;
#pragma unroll
    for (int i = 0; i < 16; ++i) {
      p[i] = __expf(pv[i] - mrun);
      rsum += p[i];
    }
    rsum += __shfl_xor(rsum, 16);
    rsum += __shfl_xor(rsum, 32);
    lrun += rsum;

    // ---- pack P -> per-wave swizzled LDS -> A-fragments ----
#pragma unroll
    for (int nt = 0; nt < 4; ++nt)
#pragma unroll
      for (int rp = 0; rp < 2; ++rp) {
        u32 pk;
        asm("v_cvt_pk_bf16_f32 %0, %1, %2" : "=v"(pk)
            : "v"(p[nt * 4 + 2 * rp]), "v"(p[nt * 4 + 2 * rp + 1]));
        *(u32*)(pbuf + ((lr * 128 + nt * 32 + lg * 8 + rp * 4) ^ ((lr & 7) << 4))) = pk;
      }
    asm volatile("s_waitcnt lgkmcnt(0)" ::: "memory");

    bf16x8 pf[2];
#pragma unroll
    for (int kk = 0; kk < 2; ++kk)
      pf[kk] = *(const bf16x8*)(pbuf + ((lr * 128 + (lg + 4 * kk) * 16) ^ ((lr & 7) << 4)));

    // ---- PV ----
    __builtin_amdgcn_s_setprio(1);
#pragma unroll
    for (int nt = 0; nt < 4; ++nt)
      for (int kk = 0; kk < kkmax; ++kk)
        oacc[nt] = __builtin_amdgcn_mfma_f32_16x16x32_bf16(pf[kk], vf[nt][kk], oacc[nt], 0, 0, 0);
    __builtin_amdgcn_s_setprio(0);
  }

  // ---- epilogue: redistribute l (lane p in 0..15 holds q-row p's sum) ----
  float lfin[4];
  int li = __float_as_int(lrun);
#pragma unroll
  for (int r = 0; r < 4; ++r)
    lfin[r] = __int_as_float(__builtin_amdgcn_ds_bpermute((4 * lg + r) << 2, li));
#pragma unroll
  for (int nt = 0; nt < 4; ++nt)
#pragma unroll
    for (int r = 0; r < 4; ++r) {
      int srow = q0 + w * 16 + lg * 4 + r;
      int col = h * DH + nt * 16 + lr;
      attnout[((size_t)b * S_LEN + srow) * DM + col] = f2bf(oacc[nt][r] / lfin[r]);
    }
}

// ---------------- launch ----------------
extern "C" void kernel_launch(void* const* d_in, const int* in_sizes, int n_in,
                              void* d_out, int out_size, void* d_ws, size_t ws_size,
                              hipStream_t stream) {
  const float* x    = (const float*)d_in[0];
  const float* Wqkv = (const float*)d_in[1];
  const float* Wo   = (const float*)d_in[2];
  const float* log_xi        = (const float*)d_in[3];
  const float* pi_gate_logit = (const float*)d_in[4];
  const float* e_gate_logit  = (const float*)d_in[5];

  u16* xb     = (u16*)d_ws;                 // 4096x1024
  u16* wqkvb  = xb + 4194304;               // 3072x1024
  u16* wob    = wqkvb + 3145728;            // 1024x1024
  u16* qkv    = wob + 1048576;              // 4096x3072
  u16* qrot   = qkv + 12582912;             // 32x2048x64
  u16* krot   = qrot + 4194304;
  u16* vt     = krot + 4194304;             // 32x64x2048
  u16* attno  = vt + 4194304;               // 4096x1024

  conv_kernel<<<4096, 256, 0, stream>>>(x, xb, 4194304);
  conv_kernel<<<3072, 256, 0, stream>>>(Wqkv, wqkvb, 3145728);
  conv_kernel<<<1024, 256, 0, stream>>>(Wo, wob, 1048576);

  gemm_bt<0><<<dim3(24, 32), 256, 0, stream>>>(xb, wqkvb, qkv, 3072, 1024);

  rope_kernel<<<dim3(32, 32), 256, 0, stream>>>(qkv, pi_gate_logit, qrot, krot, vt);

  attn_kernel<<<dim3(32, 32), 256, 0, stream>>>(qrot, krot, vt, log_xi, e_gate_logit, attno);

  gemm_bt<1><<<dim3(8, 32), 256, 0, stream>>>(attno, wob, d_out, 1024, 1024);
}

// Round 4
// 220.377 us; speedup vs baseline: 12.9660x; 12.9660x over previous
//
#include <hip/hip_runtime.h>

typedef unsigned short u16;
typedef unsigned int u32;
typedef __bf16 bf16x8 __attribute__((ext_vector_type(8)));
typedef float f32x4 __attribute__((ext_vector_type(4)));
typedef u16 u16x4 __attribute__((ext_vector_type(4)));

#define S_LEN 2048
#define NH 16
#define DH 64
#define DM 1024

#define GLDS(gp, lp) __builtin_amdgcn_global_load_lds( \
    (const __attribute__((address_space(1))) void*)(gp), \
    (__attribute__((address_space(3))) void*)(lp), 16, 0, 0)

__device__ __forceinline__ u16 f2bf(float f) {
  unsigned u = __float_as_uint(f);
  u += 0x7FFFu + ((u >> 16) & 1u);
  return (u16)(u >> 16);
}
__device__ __forceinline__ float bf2f(u16 h) {
  return __uint_as_float(((unsigned)h) << 16);
}

// ---------------- convert f32 -> bf16 ----------------
__global__ __launch_bounds__(256) void conv_kernel(const float* __restrict__ in,
                                                   u16* __restrict__ out, int n) {
  int i = (blockIdx.x * 256 + threadIdx.x) * 4;
  if (i >= n) return;
  float4 v = *(const float4*)(in + i);
  u16x4 o;
  o.x = f2bf(v.x); o.y = f2bf(v.y); o.z = f2bf(v.z); o.w = f2bf(v.w);
  *(u16x4*)(out + i) = o;
}

// ---------------- bf16 GEMM: C[M][N] = A[M][K] * B[N][K]^T ----------------
// 128x128 tile, BK=32, 4 waves, global_load_lds width-16 staging (m97 pattern).
template <int OUTF32>
__global__ __launch_bounds__(256) void gemm_bt(const u16* __restrict__ A,
                                               const u16* __restrict__ B,
                                               void* __restrict__ C,
                                               int N, int K) {
  __shared__ __align__(16) u16 smem[8192];
  u16* abuf = smem;
  u16* bbuf = smem + 4096;
  int tid = threadIdx.x;
  int w = tid >> 6, l = tid & 63, lg = l >> 4, lr = l & 15;
  int m0 = blockIdx.y * 128, n0 = blockIdx.x * 128;
  int wm = (w >> 1) * 64, wn = (w & 1) * 64;
  int NK = K >> 5;

  int srow[2], scol[2];
#pragma unroll
  for (int i = 0; i < 2; ++i) {
    srow[i] = (i * 4 + w) * 16 + (l >> 2);
    scol[i] = (l & 3) * 8;
  }

  f32x4 zero4 = {0.f, 0.f, 0.f, 0.f};
  f32x4 acc[4][4];
#pragma unroll
  for (int mt = 0; mt < 4; ++mt)
#pragma unroll
    for (int nt = 0; nt < 4; ++nt) acc[mt][nt] = zero4;

  for (int kt = 0; kt < NK; ++kt) {
    __syncthreads();  // previous iter's readers done
#pragma unroll
    for (int i = 0; i < 2; ++i) {
      GLDS(A + (size_t)(m0 + srow[i]) * K + kt * 32 + scol[i], abuf + (i * 4 + w) * 512);
      GLDS(B + (size_t)(n0 + srow[i]) * K + kt * 32 + scol[i], bbuf + (i * 4 + w) * 512);
    }
    __syncthreads();  // staged tile visible (vmcnt drained by sync)

    bf16x8 af[4], bfr[4];
#pragma unroll
    for (int mt = 0; mt < 4; ++mt)
      af[mt] = *(const bf16x8*)(abuf + (wm + mt * 16 + lr) * 32 + lg * 8);
#pragma unroll
    for (int nt = 0; nt < 4; ++nt)
      bfr[nt] = *(const bf16x8*)(bbuf + (wn + nt * 16 + lr) * 32 + lg * 8);
    __builtin_amdgcn_s_setprio(1);
#pragma unroll
    for (int mt = 0; mt < 4; ++mt)
#pragma unroll
      for (int nt = 0; nt < 4; ++nt)
        acc[mt][nt] = __builtin_amdgcn_mfma_f32_16x16x32_bf16(af[mt], bfr[nt], acc[mt][nt], 0, 0, 0);
    __builtin_amdgcn_s_setprio(0);
  }

#pragma unroll
  for (int mt = 0; mt < 4; ++mt)
#pragma unroll
    for (int nt = 0; nt < 4; ++nt)
#pragma unroll
      for (int r = 0; r < 4; ++r) {
        int row = m0 + wm + mt * 16 + lg * 4 + r;
        int col = n0 + wn + nt * 16 + lr;
        float v = acc[mt][nt][r];
        if (OUTF32) ((float*)C)[(size_t)row * N + col] = v;
        else        ((u16*)C)[(size_t)row * N + col] = f2bf(v);
      }
}

// ---------------- RoPE + head-major layout + V transpose ----------------
// Q is pre-scaled by 1/sqrt(dh) = 0.125 here.
__global__ __launch_bounds__(256) void rope_kernel(const u16* __restrict__ qkv,
                                                   const float* __restrict__ pi_gate_logit,
                                                   u16* __restrict__ qrot,
                                                   u16* __restrict__ krot,
                                                   u16* __restrict__ vt) {
  int st = blockIdx.x;   // s tile (0..31)
  int bh = blockIdx.y;   // b*16+h
  int h = bh & 15;
  int t = threadIdx.x;
  int sl = t >> 2;       // 0..63
  int pb = t & 3;
  int d0 = pb * 16;
  int s = st * 64 + sl;
  int b = bh >> 4;
  size_t rowg = (size_t)(b * S_LEN + s) * (3 * DM) + h * DH + d0;

  float pg = 1.0f / (1.0f + __expf(-pi_gate_logit[h]));
  float spos = (float)s;
  float cs[8], sn[8];
#pragma unroll
  for (int j = 0; j < 8; ++j) {
    float p = (float)(pb * 8 + j);
    float fr = exp2f((1.0f - p * 0.03125f) * 1.6514961294723187f);  // pi^(1-p/32)
    float th = (spos * fr) * pg;
    float rev = th * 0.15915494309189535f;
    rev = rev - floorf(rev);
    cs[j] = __builtin_amdgcn_cosf(rev);
    sn[j] = __builtin_amdgcn_sinf(rev);
  }

#pragma unroll
  for (int which = 0; which < 2; ++which) {
    const u16* src = qkv + rowg + (size_t)which * DM;
    float sc = which ? 1.0f : 0.125f;
    u16 in[16], ou[16];
    *(bf16x8*)(in)     = *(const bf16x8*)(src);
    *(bf16x8*)(in + 8) = *(const bf16x8*)(src + 8);
#pragma unroll
    for (int j = 0; j < 8; ++j) {
      float t1 = bf2f(in[2 * j]), t2 = bf2f(in[2 * j + 1]);
      ou[2 * j]     = f2bf((t1 * cs[j] - t2 * sn[j]) * sc);
      ou[2 * j + 1] = f2bf((t1 * sn[j] + t2 * cs[j]) * sc);
    }
    u16* dst = (which ? krot : qrot) + ((size_t)bh * S_LEN + s) * DH + d0;
    *(bf16x8*)(dst)     = *(bf16x8*)(ou);
    *(bf16x8*)(dst + 8) = *(bf16x8*)(ou + 8);
  }

  {
    const u16* src = qkv + rowg + 2 * DM;
    u16 in[16];
    *(bf16x8*)(in)     = *(const bf16x8*)(src);
    *(bf16x8*)(in + 8) = *(const bf16x8*)(src + 8);
#pragma unroll
    for (int e = 0; e < 16; ++e)
      vt[((size_t)bh * DH + d0 + e) * S_LEN + st * 64 + sl] = in[e];
  }
}

// ---------------- flash attention tile (all static indexing!) ----------------
// Swapped QK^T: sacc[nt][r] = S^T[kv=nt*16+lg*4+r][q=w*16+lr].
template <bool DIAG>
__device__ __forceinline__ void attn_tile(const u16* __restrict__ kb,
                                          const u16* __restrict__ vb,
                                          float tb, float cdec,
                                          const bf16x8 (&qf)[2],
                                          f32x4 (&oacc)[4],
                                          float& mrun, float& lrun,
                                          int lg, int lr, int il,
                                          unsigned char* pbuf) {
  f32x4 zero4 = {0.f, 0.f, 0.f, 0.f};

  // ---- QK^T ----
  f32x4 sacc[4];
#pragma unroll
  for (int nt = 0; nt < 4; ++nt) sacc[nt] = zero4;
  __builtin_amdgcn_s_setprio(1);
#pragma unroll
  for (int nt = 0; nt < 4; ++nt) {
    bf16x8 kfa = *(const bf16x8*)(kb + (nt * 16 + lr) * DH + lg * 8);
    bf16x8 kfb = *(const bf16x8*)(kb + (nt * 16 + lr) * DH + 32 + lg * 8);
    sacc[nt] = __builtin_amdgcn_mfma_f32_16x16x32_bf16(kfa, qf[0], sacc[nt], 0, 0, 0);
    sacc[nt] = __builtin_amdgcn_mfma_f32_16x16x32_bf16(kfb, qf[1], sacc[nt], 0, 0, 0);
  }
  __builtin_amdgcn_s_setprio(0);

  // ---- V fragments (issue early; latency hides under softmax VALU) ----
  bf16x8 vf[4][2];
#pragma unroll
  for (int nt = 0; nt < 4; ++nt)
#pragma unroll
    for (int kk = 0; kk < 2; ++kk)
      vf[nt][kk] = *(const bf16x8*)(vb + (size_t)(nt * 16 + lr) * S_LEN + kk * 32 + lg * 8);

  // ---- scores + bias (+ causal mask on diagonal) ----
  float pv[16];
  float base = tb + (float)(lg * 4) * cdec;
#pragma unroll
  for (int nt = 0; nt < 4; ++nt)
#pragma unroll
    for (int r = 0; r < 4; ++r) {
      float v = sacc[nt][r] + fmaf((float)(nt * 16 + r), cdec, base);
      if (DIAG) {
        int jl = nt * 16 + lg * 4 + r;
        v = (jl <= il) ? v : -1e30f;
      }
      pv[nt * 4 + r] = v;
    }

  // ---- row max: in-lane tree + 2 shuffles ----
  float m1 = pv[0];
#pragma unroll
  for (int i = 1; i < 16; ++i) m1 = fmaxf(m1, pv[i]);
  m1 = fmaxf(m1, __shfl_xor(m1, 16));
  m1 = fmaxf(m1, __shfl_xor(m1, 32));

  // ---- defer-max rescale (THR=8) ----
  if (__ballot(m1 > mrun + 8.f)) {
    float mnew = fmaxf(mrun, m1);
    float fac = __expf(mrun - mnew);
    mrun = mnew;
    lrun *= fac;
    int fi = __float_as_int(fac);
    float facr[4];
#pragma unroll
    for (int r = 0; r < 4; ++r)
      facr[r] = __int_as_float(__builtin_amdgcn_ds_bpermute((4 * lg + r) << 2, fi));
#pragma unroll
    for (int nt = 0; nt < 4; ++nt)
#pragma unroll
      for (int r = 0; r < 4; ++r) oacc[nt][r] *= facr[r];
  }

  // ---- exp + row sum ----
  float p[16];
  float rsum = 0.f;
#pragma unroll
  for (int i = 0; i < 16; ++i) {
    p[i] = __expf(pv[i] - mrun);
    rsum += p[i];
  }
  rsum += __shfl_xor(rsum, 16);
  rsum += __shfl_xor(rsum, 32);
  lrun += rsum;

  // ---- pack P -> per-wave swizzled LDS -> A-fragments ----
#pragma unroll
  for (int nt = 0; nt < 4; ++nt)
#pragma unroll
    for (int rp = 0; rp < 2; ++rp) {
      u32 pk;
      asm("v_cvt_pk_bf16_f32 %0, %1, %2" : "=v"(pk)
          : "v"(p[nt * 4 + 2 * rp]), "v"(p[nt * 4 + 2 * rp + 1]));
      *(u32*)(pbuf + ((lr * 128 + nt * 32 + lg * 8 + rp * 4) ^ ((lr & 7) << 4))) = pk;
    }
  asm volatile("s_waitcnt lgkmcnt(0)" ::: "memory");

  bf16x8 pf[2];
#pragma unroll
  for (int kk = 0; kk < 2; ++kk)
    pf[kk] = *(const bf16x8*)(pbuf + ((lr * 128 + (lg + 4 * kk) * 16) ^ ((lr & 7) << 4)));

  // ---- PV ----
  __builtin_amdgcn_s_setprio(1);
#pragma unroll
  for (int nt = 0; nt < 4; ++nt)
#pragma unroll
    for (int kk = 0; kk < 2; ++kk)
      oacc[nt] = __builtin_amdgcn_mfma_f32_16x16x32_bf16(pf[kk], vf[nt][kk], oacc[nt], 0, 0, 0);
  __builtin_amdgcn_s_setprio(0);
}

// Barrier-free flash attention: K/V fragments direct from global (L1/L2-hit),
// per-wave private P buffer, heavy-first grid (qt = 31 - blockIdx.y).
__global__ __launch_bounds__(256) void attn_kernel(const u16* __restrict__ qrot,
                                                   const u16* __restrict__ krot,
                                                   const u16* __restrict__ vt,
                                                   const float* __restrict__ log_xi,
                                                   const float* __restrict__ e_gate_logit,
                                                   u16* __restrict__ attnout) {
  int bh = blockIdx.x;
  int qt = 31 - blockIdx.y;
  int b = bh >> 4, h = bh & 15;
  int tid = threadIdx.x, w = tid >> 6, l = tid & 63, lg = l >> 4, lr = l & 15;
  int q0 = qt * 64;
  int il = w * 16 + lr;  // this lane's q-row, local to the 64-row tile

  float eg = 1.0f / (1.0f + __expf(-e_gate_logit[h]));
  float cdec = eg * __expf(-log_xi[h]);  // e_g / xi

  __shared__ __align__(16) unsigned char smem[8192];
  unsigned char* pbuf = smem + (w << 11);  // 2KB per wave, private

  const size_t bhS = (size_t)bh * S_LEN;
  const u16* kb0 = krot + bhS * DH;
  const u16* vb0 = vt + (size_t)bh * DH * S_LEN;

  bf16x8 qf[2];
  {
    const u16* qp = qrot + (bhS + q0 + il) * DH + lg * 8;
    qf[0] = *(const bf16x8*)(qp);
    qf[1] = *(const bf16x8*)(qp + 32);
  }

  f32x4 zero4 = {0.f, 0.f, 0.f, 0.f};
  f32x4 oacc[4];
#pragma unroll
  for (int nt = 0; nt < 4; ++nt) oacc[nt] = zero4;
  float mrun = -1e30f, lrun = 0.f;

  float step = 64.f * cdec;
  float tb = 0.f;
  for (int t = 0; t < qt; ++t, tb += step)
    attn_tile<false>(kb0 + (size_t)t * 64 * DH, vb0 + t * 64, tb, cdec,
                     qf, oacc, mrun, lrun, lg, lr, il, pbuf);
  attn_tile<true>(kb0 + (size_t)qt * 64 * DH, vb0 + qt * 64, tb, cdec,
                  qf, oacc, mrun, lrun, lg, lr, il, pbuf);

  // ---- epilogue: redistribute l (lane p in 0..15 holds q-row p's sum) ----
  float lfin[4];
  int li = __float_as_int(lrun);
#pragma unroll
  for (int r = 0; r < 4; ++r)
    lfin[r] = __int_as_float(__builtin_amdgcn_ds_bpermute((4 * lg + r) << 2, li));
#pragma unroll
  for (int nt = 0; nt < 4; ++nt)
#pragma unroll
    for (int r = 0; r < 4; ++r) {
      int srow = q0 + w * 16 + lg * 4 + r;
      int col = h * DH + nt * 16 + lr;
      attnout[((size_t)b * S_LEN + srow) * DM + col] = f2bf(oacc[nt][r] / lfin[r]);
    }
}

// ---------------- launch ----------------
extern "C" void kernel_launch(void* const* d_in, const int* in_sizes, int n_in,
                              void* d_out, int out_size, void* d_ws, size_t ws_size,
                              hipStream_t stream) {
  const float* x    = (const float*)d_in[0];
  const float* Wqkv = (const float*)d_in[1];
  const float* Wo   = (const float*)d_in[2];
  const float* log_xi        = (const float*)d_in[3];
  const float* pi_gate_logit = (const float*)d_in[4];
  const float* e_gate_logit  = (const float*)d_in[5];

  u16* xb     = (u16*)d_ws;                 // 4096x1024
  u16* wqkvb  = xb + 4194304;               // 3072x1024
  u16* wob    = wqkvb + 3145728;            // 1024x1024
  u16* qkv    = wob + 1048576;              // 4096x3072
  u16* qrot   = qkv + 12582912;             // 32x2048x64
  u16* krot   = qrot + 4194304;
  u16* vt     = krot + 4194304;             // 32x64x2048
  u16* attno  = vt + 4194304;               // 4096x1024

  conv_kernel<<<4096, 256, 0, stream>>>(x, xb, 4194304);
  conv_kernel<<<3072, 256, 0, stream>>>(Wqkv, wqkvb, 3145728);
  conv_kernel<<<1024, 256, 0, stream>>>(Wo, wob, 1048576);

  gemm_bt<0><<<dim3(24, 32), 256, 0, stream>>>(xb, wqkvb, qkv, 3072, 1024);

  rope_kernel<<<dim3(32, 32), 256, 0, stream>>>(qkv, pi_gate_logit, qrot, krot, vt);

  attn_kernel<<<dim3(32, 32), 256, 0, stream>>>(qrot, krot, vt, log_xi, e_gate_logit, attno);

  gemm_bt<1><<<dim3(8, 32), 256, 0, stream>>>(attno, wob, d_out, 1024, 1024);
}

// Round 5
// 128.763 us; speedup vs baseline: 22.1912x; 1.7115x over previous
//
#include <hip/hip_runtime.h>

typedef unsigned short u16;
typedef unsigned int u32;
typedef __bf16 bf16x8 __attribute__((ext_vector_type(8)));
typedef float f32x4 __attribute__((ext_vector_type(4)));
typedef u16 u16x4 __attribute__((ext_vector_type(4)));

#define S_LEN 2048
#define NH 16
#define DH 64
#define DM 1024

#define GLDS(gp, lp) __builtin_amdgcn_global_load_lds( \
    (const __attribute__((address_space(1))) void*)(gp), \
    (__attribute__((address_space(3))) void*)(lp), 16, 0, 0)

__device__ __forceinline__ u16 f2bf(float f) {
  unsigned u = __float_as_uint(f);
  u += 0x7FFFu + ((u >> 16) & 1u);
  return (u16)(u >> 16);
}
__device__ __forceinline__ float bf2f(u16 h) {
  return __uint_as_float(((unsigned)h) << 16);
}

// ---------------- convert f32 -> bf16 ----------------
__global__ __launch_bounds__(256) void conv_kernel(const float* __restrict__ in,
                                                   u16* __restrict__ out, int n) {
  int i = (blockIdx.x * 256 + threadIdx.x) * 4;
  if (i >= n) return;
  float4 v = *(const float4*)(in + i);
  u16x4 o;
  o.x = f2bf(v.x); o.y = f2bf(v.y); o.z = f2bf(v.z); o.w = f2bf(v.w);
  *(u16x4*)(out + i) = o;
}

// ---------------- bf16 GEMM: C[M][N] = A[M][K] * B[N][K]^T ----------------
// 128x128 tile, BK=32, 4 waves, global_load_lds width-16 staging (m97 pattern).
template <int OUTF32>
__global__ __launch_bounds__(256) void gemm_bt(const u16* __restrict__ A,
                                               const u16* __restrict__ B,
                                               void* __restrict__ C,
                                               int N, int K) {
  __shared__ __align__(16) u16 smem[8192];
  u16* abuf = smem;
  u16* bbuf = smem + 4096;
  int tid = threadIdx.x;
  int w = tid >> 6, l = tid & 63, lg = l >> 4, lr = l & 15;
  int m0 = blockIdx.y * 128, n0 = blockIdx.x * 128;
  int wm = (w >> 1) * 64, wn = (w & 1) * 64;
  int NK = K >> 5;

  int srow[2], scol[2];
#pragma unroll
  for (int i = 0; i < 2; ++i) {
    srow[i] = (i * 4 + w) * 16 + (l >> 2);
    scol[i] = (l & 3) * 8;
  }

  f32x4 zero4 = {0.f, 0.f, 0.f, 0.f};
  f32x4 acc[4][4];
#pragma unroll
  for (int mt = 0; mt < 4; ++mt)
#pragma unroll
    for (int nt = 0; nt < 4; ++nt) acc[mt][nt] = zero4;

  for (int kt = 0; kt < NK; ++kt) {
    __syncthreads();  // previous iter's readers done
#pragma unroll
    for (int i = 0; i < 2; ++i) {
      GLDS(A + (size_t)(m0 + srow[i]) * K + kt * 32 + scol[i], abuf + (i * 4 + w) * 512);
      GLDS(B + (size_t)(n0 + srow[i]) * K + kt * 32 + scol[i], bbuf + (i * 4 + w) * 512);
    }
    __syncthreads();  // staged tile visible (vmcnt drained by sync)

    bf16x8 af[4], bfr[4];
#pragma unroll
    for (int mt = 0; mt < 4; ++mt)
      af[mt] = *(const bf16x8*)(abuf + (wm + mt * 16 + lr) * 32 + lg * 8);
#pragma unroll
    for (int nt = 0; nt < 4; ++nt)
      bfr[nt] = *(const bf16x8*)(bbuf + (wn + nt * 16 + lr) * 32 + lg * 8);
    __builtin_amdgcn_s_setprio(1);
#pragma unroll
    for (int mt = 0; mt < 4; ++mt)
#pragma unroll
      for (int nt = 0; nt < 4; ++nt)
        acc[mt][nt] = __builtin_amdgcn_mfma_f32_16x16x32_bf16(af[mt], bfr[nt], acc[mt][nt], 0, 0, 0);
    __builtin_amdgcn_s_setprio(0);
  }

#pragma unroll
  for (int mt = 0; mt < 4; ++mt)
#pragma unroll
    for (int nt = 0; nt < 4; ++nt)
#pragma unroll
      for (int r = 0; r < 4; ++r) {
        int row = m0 + wm + mt * 16 + lg * 4 + r;
        int col = n0 + wn + nt * 16 + lr;
        float v = acc[mt][nt][r];
        if (OUTF32) ((float*)C)[(size_t)row * N + col] = v;
        else        ((u16*)C)[(size_t)row * N + col] = f2bf(v);
      }
}

// ---------------- RoPE + head-major layout + V transpose ----------------
// Q is pre-scaled by 1/sqrt(dh) = 0.125 here.
__global__ __launch_bounds__(256) void rope_kernel(const u16* __restrict__ qkv,
                                                   const float* __restrict__ pi_gate_logit,
                                                   u16* __restrict__ qrot,
                                                   u16* __restrict__ krot,
                                                   u16* __restrict__ vt) {
  int st = blockIdx.x;   // s tile (0..31)
  int bh = blockIdx.y;   // b*16+h
  int h = bh & 15;
  int t = threadIdx.x;
  int sl = t >> 2;       // 0..63
  int pb = t & 3;
  int d0 = pb * 16;
  int s = st * 64 + sl;
  int b = bh >> 4;
  size_t rowg = (size_t)(b * S_LEN + s) * (3 * DM) + h * DH + d0;

  float pg = 1.0f / (1.0f + __expf(-pi_gate_logit[h]));
  float spos = (float)s;
  float cs[8], sn[8];
#pragma unroll
  for (int j = 0; j < 8; ++j) {
    float p = (float)(pb * 8 + j);
    float fr = exp2f((1.0f - p * 0.03125f) * 1.6514961294723187f);  // pi^(1-p/32)
    float th = (spos * fr) * pg;
    float rev = th * 0.15915494309189535f;
    rev = rev - floorf(rev);
    cs[j] = __builtin_amdgcn_cosf(rev);
    sn[j] = __builtin_amdgcn_sinf(rev);
  }

#pragma unroll
  for (int which = 0; which < 2; ++which) {
    const u16* src = qkv + rowg + (size_t)which * DM;
    float sc = which ? 1.0f : 0.125f;
    u16 in[16], ou[16];
    *(bf16x8*)(in)     = *(const bf16x8*)(src);
    *(bf16x8*)(in + 8) = *(const bf16x8*)(src + 8);
#pragma unroll
    for (int j = 0; j < 8; ++j) {
      float t1 = bf2f(in[2 * j]), t2 = bf2f(in[2 * j + 1]);
      ou[2 * j]     = f2bf((t1 * cs[j] - t2 * sn[j]) * sc);
      ou[2 * j + 1] = f2bf((t1 * sn[j] + t2 * cs[j]) * sc);
    }
    u16* dst = (which ? krot : qrot) + ((size_t)bh * S_LEN + s) * DH + d0;
    *(bf16x8*)(dst)     = *(bf16x8*)(ou);
    *(bf16x8*)(dst + 8) = *(bf16x8*)(ou + 8);
  }

  {
    const u16* src = qkv + rowg + 2 * DM;
    u16 in[16];
    *(bf16x8*)(in)     = *(const bf16x8*)(src);
    *(bf16x8*)(in + 8) = *(const bf16x8*)(src + 8);
#pragma unroll
    for (int e = 0; e < 16; ++e)
      vt[((size_t)bh * DH + d0 + e) * S_LEN + st * 64 + sl] = in[e];
  }
}

// ---------------- flash attention tile compute (static indexing) ----------------
// Swapped QK^T: sacc[nt][r] = S^T[kv=nt*16+lg*4+r][q=w*16+lr].
template <bool DIAG>
__device__ __forceinline__ void attn_tile(const unsigned char* __restrict__ kbuf,
                                          const unsigned char* __restrict__ vbuf,
                                          float tb, float cdec,
                                          const bf16x8 (&qf)[2],
                                          f32x4 (&oacc)[4],
                                          float& mrun, float& lrun,
                                          int lg, int lr, int il,
                                          unsigned char* pbuf) {
  f32x4 zero4 = {0.f, 0.f, 0.f, 0.f};

  // ---- QK^T from LDS ----
  f32x4 sacc[4];
#pragma unroll
  for (int nt = 0; nt < 4; ++nt) sacc[nt] = zero4;
  __builtin_amdgcn_s_setprio(1);
#pragma unroll
  for (int nt = 0; nt < 4; ++nt)
#pragma unroll
    for (int kk = 0; kk < 2; ++kk) {
      int row = nt * 16 + lr;
      int sl_ = lg + kk * 4;
      bf16x8 kf = *(const bf16x8*)(kbuf + row * 128 + ((sl_ ^ (row & 7)) << 4));
      sacc[nt] = __builtin_amdgcn_mfma_f32_16x16x32_bf16(kf, qf[kk], sacc[nt], 0, 0, 0);
    }
  __builtin_amdgcn_s_setprio(0);

  // ---- scores + bias (+ causal mask on diagonal) ----
  float pv[16];
  float base = tb + (float)(lg * 4) * cdec;
#pragma unroll
  for (int nt = 0; nt < 4; ++nt)
#pragma unroll
    for (int r = 0; r < 4; ++r) {
      float v = sacc[nt][r] + fmaf((float)(nt * 16 + r), cdec, base);
      if (DIAG) {
        int jl = nt * 16 + lg * 4 + r;
        v = (jl <= il) ? v : -1e30f;
      }
      pv[nt * 4 + r] = v;
    }

  // ---- row max: in-lane tree + 2 shuffles ----
  float m1 = pv[0];
#pragma unroll
  for (int i = 1; i < 16; ++i) m1 = fmaxf(m1, pv[i]);
  m1 = fmaxf(m1, __shfl_xor(m1, 16));
  m1 = fmaxf(m1, __shfl_xor(m1, 32));

  // ---- defer-max rescale (THR=8) ----
  if (__ballot(m1 > mrun + 8.f)) {
    float mnew = fmaxf(mrun, m1);
    float fac = __expf(mrun - mnew);
    mrun = mnew;
    lrun *= fac;
    int fi = __float_as_int(fac);
    float facr[4];
#pragma unroll
    for (int r = 0; r < 4; ++r)
      facr[r] = __int_as_float(__builtin_amdgcn_ds_bpermute((4 * lg + r) << 2, fi));
#pragma unroll
    for (int nt = 0; nt < 4; ++nt)
#pragma unroll
      for (int r = 0; r < 4; ++r) oacc[nt][r] *= facr[r];
  }

  // ---- exp + row sum ----
  float p[16];
  float rsum = 0.f;
#pragma unroll
  for (int i = 0; i < 16; ++i) {
    p[i] = __expf(pv[i] - mrun);
    rsum += p[i];
  }
  rsum += __shfl_xor(rsum, 16);
  rsum += __shfl_xor(rsum, 32);
  lrun += rsum;

  // ---- pack P -> per-wave swizzled LDS -> A-fragments ----
#pragma unroll
  for (int nt = 0; nt < 4; ++nt)
#pragma unroll
    for (int rp = 0; rp < 2; ++rp) {
      u32 pk;
      asm("v_cvt_pk_bf16_f32 %0, %1, %2" : "=v"(pk)
          : "v"(p[nt * 4 + 2 * rp]), "v"(p[nt * 4 + 2 * rp + 1]));
      *(u32*)(pbuf + ((lr * 128 + nt * 32 + lg * 8 + rp * 4) ^ ((lr & 7) << 4))) = pk;
    }
  asm volatile("s_waitcnt lgkmcnt(0)" ::: "memory");

  bf16x8 pf[2];
#pragma unroll
  for (int kk = 0; kk < 2; ++kk)
    pf[kk] = *(const bf16x8*)(pbuf + ((lr * 128 + (lg + 4 * kk) * 16) ^ ((lr & 7) << 4)));

  // ---- PV from LDS ----
  __builtin_amdgcn_s_setprio(1);
#pragma unroll
  for (int nt = 0; nt < 4; ++nt)
#pragma unroll
    for (int kk = 0; kk < 2; ++kk) {
      int row = nt * 16 + lr;
      int sl_ = lg + kk * 4;
      bf16x8 vf = *(const bf16x8*)(vbuf + row * 128 + ((sl_ ^ (row & 7)) << 4));
      oacc[nt] = __builtin_amdgcn_mfma_f32_16x16x32_bf16(pf[kk], vf, oacc[nt], 0, 0, 0);
    }
  __builtin_amdgcn_s_setprio(0);
}

// Flash attention: double-buffered LDS K/V (ONE barrier per tile), reg
// prefetch one tile ahead, heavy-first grid (qt = 31 - blockIdx.y).
__global__ __launch_bounds__(256, 3) void attn_kernel(const u16* __restrict__ qrot,
                                                      const u16* __restrict__ krot,
                                                      const u16* __restrict__ vt,
                                                      const float* __restrict__ log_xi,
                                                      const float* __restrict__ e_gate_logit,
                                                      u16* __restrict__ attnout) {
  int bh = blockIdx.x;
  int qt = 31 - blockIdx.y;
  int b = bh >> 4, h = bh & 15;
  int tid = threadIdx.x, w = tid >> 6, l = tid & 63, lg = l >> 4, lr = l & 15;
  int q0 = qt * 64;
  int il = w * 16 + lr;  // this lane's q-row, local to the 64-row tile

  float eg = 1.0f / (1.0f + __expf(-e_gate_logit[h]));
  float cdec = eg * __expf(-log_xi[h]);  // e_g / xi

  __shared__ __align__(16) unsigned char smem[40960];
  // [0:16384) kbuf[2], [16384:32768) vbuf[2], [32768:40960) pbuf per-wave
  unsigned char* pbuf = smem + 32768 + (w << 11);

  const size_t bhS = (size_t)bh * S_LEN;
  const u16* kb0 = krot + bhS * DH;
  const u16* vb0 = vt + (size_t)bh * DH * S_LEN;

  bf16x8 qf[2];
  {
    const u16* qp = qrot + (bhS + q0 + il) * DH + lg * 8;
    qf[0] = *(const bf16x8*)(qp);
    qf[1] = *(const bf16x8*)(qp + 32);
  }

  // staging geometry: 512 chunks of 16B per 8KB tile; this thread's 2 chunks
  int c0 = tid, c1 = 256 + tid;
  int row0 = c0 >> 3, sl0 = c0 & 7;
  int row1 = c1 >> 3, sl1 = c1 & 7;

  bf16x8 kr[2], vr[2];
  auto load_kv = [&](int t) {
    kr[0] = *(const bf16x8*)(kb0 + (size_t)(t * 64 + row0) * DH + sl0 * 8);
    kr[1] = *(const bf16x8*)(kb0 + (size_t)(t * 64 + row1) * DH + sl1 * 8);
    vr[0] = *(const bf16x8*)(vb0 + (size_t)row0 * S_LEN + t * 64 + sl0 * 8);
    vr[1] = *(const bf16x8*)(vb0 + (size_t)row1 * S_LEN + t * 64 + sl1 * 8);
  };
  auto stage = [&](int p) {
    unsigned char* kb = smem + p * 8192;
    unsigned char* vb = smem + 16384 + p * 8192;
    *(bf16x8*)(kb + row0 * 128 + ((sl0 ^ (row0 & 7)) << 4)) = kr[0];
    *(bf16x8*)(kb + row1 * 128 + ((sl1 ^ (row1 & 7)) << 4)) = kr[1];
    *(bf16x8*)(vb + row0 * 128 + ((sl0 ^ (row0 & 7)) << 4)) = vr[0];
    *(bf16x8*)(vb + row1 * 128 + ((sl1 ^ (row1 & 7)) << 4)) = vr[1];
  };

  f32x4 zero4 = {0.f, 0.f, 0.f, 0.f};
  f32x4 oacc[4];
#pragma unroll
  for (int nt = 0; nt < 4; ++nt) oacc[nt] = zero4;
  float mrun = -1e30f, lrun = 0.f;

  load_kv(0);
  float step = 64.f * cdec;
  float tb = 0.f;
  int p = 0;
  for (int t = 0; t < qt; ++t, tb += step, p ^= 1) {
    stage(p);           // waits vmcnt for kr/vr internally
    load_kv(t + 1);     // prefetch next tile; drains at next stage()
    __syncthreads();    // staged writes visible; prev buffer's readers done
    attn_tile<false>(smem + p * 8192, smem + 16384 + p * 8192, tb, cdec,
                     qf, oacc, mrun, lrun, lg, lr, il, pbuf);
  }
  stage(p);
  __syncthreads();
  attn_tile<true>(smem + p * 8192, smem + 16384 + p * 8192, tb, cdec,
                  qf, oacc, mrun, lrun, lg, lr, il, pbuf);

  // ---- epilogue: redistribute l (lane p in 0..15 holds q-row p's sum) ----
  float lfin[4];
  int li = __float_as_int(lrun);
#pragma unroll
  for (int r = 0; r < 4; ++r)
    lfin[r] = __int_as_float(__builtin_amdgcn_ds_bpermute((4 * lg + r) << 2, li));
#pragma unroll
  for (int nt = 0; nt < 4; ++nt)
#pragma unroll
    for (int r = 0; r < 4; ++r) {
      int srow = q0 + w * 16 + lg * 4 + r;
      int col = h * DH + nt * 16 + lr;
      attnout[((size_t)b * S_LEN + srow) * DM + col] = f2bf(oacc[nt][r] / lfin[r]);
    }
}

// ---------------- launch ----------------
extern "C" void kernel_launch(void* const* d_in, const int* in_sizes, int n_in,
                              void* d_out, int out_size, void* d_ws, size_t ws_size,
                              hipStream_t stream) {
  const float* x    = (const float*)d_in[0];
  const float* Wqkv = (const float*)d_in[1];
  const float* Wo   = (const float*)d_in[2];
  const float* log_xi        = (const float*)d_in[3];
  const float* pi_gate_logit = (const float*)d_in[4];
  const float* e_gate_logit  = (const float*)d_in[5];

  u16* xb     = (u16*)d_ws;                 // 4096x1024
  u16* wqkvb  = xb + 4194304;               // 3072x1024
  u16* wob    = wqkvb + 3145728;            // 1024x1024
  u16* qkv    = wob + 1048576;              // 4096x3072
  u16* qrot   = qkv + 12582912;             // 32x2048x64
  u16* krot   = qrot + 4194304;
  u16* vt     = krot + 4194304;             // 32x64x2048
  u16* attno  = vt + 4194304;               // 4096x1024

  conv_kernel<<<4096, 256, 0, stream>>>(x, xb, 4194304);
  conv_kernel<<<3072, 256, 0, stream>>>(Wqkv, wqkvb, 3145728);
  conv_kernel<<<1024, 256, 0, stream>>>(Wo, wob, 1048576);

  gemm_bt<0><<<dim3(24, 32), 256, 0, stream>>>(xb, wqkvb, qkv, 3072, 1024);

  rope_kernel<<<dim3(32, 32), 256, 0, stream>>>(qkv, pi_gate_logit, qrot, krot, vt);

  attn_kernel<<<dim3(32, 32), 256, 0, stream>>>(qrot, krot, vt, log_xi, e_gate_logit, attno);

  gemm_bt<1><<<dim3(8, 32), 256, 0, stream>>>(attno, wob, d_out, 1024, 1024);
}